// Round 6
// baseline (635.285 us; speedup 1.0000x reference)
//
#include <hip/hip_runtime.h>
#include <hip/hip_bf16.h>

#define D 256
#define H 8
#define DK 32

typedef unsigned short ushort_t;
typedef unsigned int uint_t;
typedef __attribute__((ext_vector_type(4))) float floatx4;
typedef __attribute__((ext_vector_type(2))) float floatx2;
typedef __attribute__((ext_vector_type(8))) short shortx8;
typedef __attribute__((ext_vector_type(8))) unsigned short ushortx8;

typedef __attribute__((address_space(3))) void lds_void_t;
typedef const __attribute__((address_space(1))) void gbl_void_t;

__device__ __forceinline__ float b2f(ushort_t u) {
    return __uint_as_float(((uint_t)u) << 16);
}
__device__ __forceinline__ floatx2 b2x2(uint_t u) {
    floatx2 r;
    r.x = __uint_as_float(u << 16);
    r.y = __uint_as_float(u & 0xffff0000u);
    return r;
}
__device__ __forceinline__ ushort_t f2b(float f) {
    uint_t u = __float_as_uint(f);
    uint_t r = (u + 0x7FFFu + ((u >> 16) & 1u)) >> 16;   // RNE
    return (ushort_t)r;
}
__device__ __forceinline__ void async_cp16(const void* g, void* l) {
    __builtin_amdgcn_global_load_lds((gbl_void_t*)g, (lds_void_t*)l, 16, 0, 0);
}

// ---------------------------------------------------------------------------
// feats fp32 -> bf16 (vectorized)
// ---------------------------------------------------------------------------
__global__ void cvt_bf16(const float* __restrict__ in, ushort_t* __restrict__ out, size_t n4) {
    size_t i = (size_t)blockIdx.x * blockDim.x + threadIdx.x;
    if (i >= n4) return;
    float4 v = ((const float4*)in)[i];
    ushort4 o;
    o.x = f2b(v.x); o.y = f2b(v.y); o.z = f2b(v.z); o.w = f2b(v.w);
    ((ushort4*)out)[i] = o;
}

__global__ void zero_int(int* __restrict__ p, int n) {
    int i = blockIdx.x * blockDim.x + threadIdx.x;
    if (i < n) p[i] = 0;
}

// ---------------------------------------------------------------------------
// Fold per-head w_att/w_msg into Wk/Wv (fp32, D x D) and biases.
// ---------------------------------------------------------------------------
__global__ void fold_weights(const float* __restrict__ Wk, const float* __restrict__ bk,
                             const float* __restrict__ Wv, const float* __restrict__ bv,
                             const float* __restrict__ w_att, const float* __restrict__ w_msg,
                             float* __restrict__ Wkc, float* __restrict__ bkc,
                             float* __restrict__ Wvc, float* __restrict__ bvc) {
    int r = blockIdx.x, et = blockIdx.y, which = blockIdx.z;
    int tid = threadIdx.x;
    const float* Wsrc = (which ? Wv : Wk) + (size_t)et * D * D + (size_t)r * D;
    const float* wt   = (which ? w_msg : w_att) + (size_t)et * H * DK * DK;
    float* Wdst = (which ? Wvc : Wkc) + (size_t)et * D * D;
    __shared__ float wrow[D];
    wrow[tid] = Wsrc[tid];
    __syncthreads();
    int h = tid >> 5, j = tid & 31;
    const float* wth = wt + h * DK * DK;
    float acc = 0.f;
#pragma unroll 8
    for (int i = 0; i < DK; i++) acc += wrow[h * 32 + i] * wth[i * 32 + j];
    Wdst[(size_t)r * D + tid] = acc;
    if (r == 0) {
        const float* bsrc = (which ? bv : bk) + et * D;
        float* bdst = (which ? bvc : bkc) + et * D;
        float bacc = 0.f;
#pragma unroll 8
        for (int i = 0; i < DK; i++) bacc += bsrc[h * 32 + i] * wth[i * 32 + j];
        bdst[tid] = bacc;
    }
}

// ---------------------------------------------------------------------------
// Pack transposed bf16 weights:
//   WT_all[t][n][k], n in [0,768): {Wq | Wkc | Wvc}[t][k][n%256]
//   WaT[t][n][k] = Wa[t][k][n]
//   bias_all[t][n] = {bq | bkc | bvc}
// ---------------------------------------------------------------------------
__global__ void pack_weights(const float* __restrict__ Wq, const float* __restrict__ bq,
                             const float* __restrict__ Wkc, const float* __restrict__ bkc,
                             const float* __restrict__ Wvc, const float* __restrict__ bvc,
                             const float* __restrict__ Wa,
                             ushort_t* __restrict__ WT_all, ushort_t* __restrict__ WaT,
                             float* __restrict__ bias_all) {
    int idx = blockIdx.x * blockDim.x + threadIdx.x;
    const int NW = 2 * 768 * 256;
    if (idx < NW) {
        int t = idx / (768 * 256);
        int rem = idx - t * 768 * 256;
        int n = rem >> 8, k = rem & 255;
        int sec = n >> 8, nn = n & 255;
        const float* W = (sec == 0) ? Wq : (sec == 1) ? Wkc : Wvc;
        WT_all[idx] = f2b(W[(size_t)t * D * D + (size_t)k * D + nn]);
    } else if (idx < NW + 2 * 256 * 256) {
        int r = idx - NW;
        int t = r / (256 * 256);
        int rem = r - t * 256 * 256;
        int n = rem >> 8, k = rem & 255;
        WaT[r] = f2b(Wa[(size_t)t * D * D + (size_t)k * D + n]);
    }
    if (idx < 2 * 768) {
        int t = idx / 768, n = idx % 768;
        int sec = n >> 8, nn = n & 255;
        const float* b = (sec == 0) ? bq : (sec == 1) ? bkc : bvc;
        bias_all[idx] = b[t * D + nn];
    }
}

// ---------------------------------------------------------------------------
// bf16 MFMA GEMM: C(M x Ncols) = A(M x 256) @ BT^T + bias, bf16 out at
// col offset cShift, stride ldc. blockIdx.z = type. 128x128 tile, TKK=32,
// 2-phase double-buffer with counted vmcnt(4).
// T2 LDS XOR-swizzle (both-sides, rule #21): LDS rows are 64B = 4 x 16B
// slots; linear layout 8-way bank-conflicts on ds_read_b128 (rows 2 apart
// alias). LDS slot c of row R holds GLOBAL slot c ^ ((R>>1)&3) (pre-swizzled
// source col, since global_load_lds dest is linear); reads use slot
// fq ^ ((fr>>1)&3)  -> 2-way max (free). Pre-committed read per m252 regime
// gate: if conflicts ~0 but dur unchanged, 2-phase critical path confirmed.
// XCD-chunked bijective remap (m204), col-tile fastest for A L2 reuse.
// ---------------------------------------------------------------------------
#define TM 128
#define TN 128
#define TKK 32
__launch_bounds__(256)
__global__ void gemm_mfma(const ushort_t* __restrict__ A0, int lda, size_t aStr,
                          const ushort_t* __restrict__ BT0, size_t bStr,
                          const float* __restrict__ bias0, int biasStr,
                          ushort_t* __restrict__ C0, int ldc, size_t cStr,
                          int cShift, int M) {
    __shared__ ushort_t As[2][TM * TKK];   // 2 x 8 KB
    __shared__ ushort_t Bs[2][TN * TKK];   // 2 x 8 KB
    int tid = threadIdx.x;
    int w = tid >> 6, lane = tid & 63;
    int t = blockIdx.z;
    const ushort_t* A  = A0 + (size_t)t * aStr;
    const ushort_t* BT = BT0 + (size_t)t * bStr;
    const float* bias  = bias0 + (size_t)t * biasStr;
    ushort_t* C        = C0 + (size_t)t * cStr;

    // --- XCD-chunked bijective swizzle, col-tile fastest ---
    int nwg  = gridDim.x * gridDim.y;
    int orig = blockIdx.y * gridDim.x + blockIdx.x;
    int q = nwg >> 3, r = nwg & 7;
    int xcd = orig & 7, loc = orig >> 3;
    int wgid = (xcd < r ? xcd * (q + 1) : r * (q + 1) + (xcd - r) * q) + loc;
    int ncol = gridDim.y;
    int rowt = wgid / ncol;
    int colt = wgid - rowt * ncol;
    int bm = rowt * TM;
    int bn = colt * TN;

    int wm = (w & 1) * 64, wn = (w >> 1) * 64;

    floatx4 acc[4][4] = {};

    int srow = lane >> 2;                                  // row within 16-row cp16 group
    int sswz = ((lane & 3) ^ ((srow >> 1) & 3)) * 8;       // pre-swizzled source col (ushorts)
    int fr = lane & 15, fq = lane >> 4;
    int rswz = (fq ^ ((fr >> 1) & 3)) * 8;                 // swizzled read col (ushorts)

#define GEMM_STAGE(b, kc)                                                     \
    {                                                                         \
        _Pragma("unroll")                                                     \
        for (int j = 0; j < 2; j++) {                                         \
            int rr = w * 32 + j * 16;                                         \
            int gr = bm + rr + srow; if (gr >= M) gr = M - 1;                 \
            async_cp16(A + (size_t)gr * lda + (kc) + sswz, As[b] + rr * TKK); \
            int gn = bn + rr + srow;                                          \
            async_cp16(BT + (size_t)gn * 256 + (kc) + sswz, Bs[b] + rr * TKK);\
        }                                                                     \
    }

    GEMM_STAGE(0, 0);
#pragma unroll
    for (int s = 0; s < 8; s++) {
        int cur = s & 1;
        if (s < 7) {
            GEMM_STAGE(cur ^ 1, (s + 1) * TKK);
            __builtin_amdgcn_s_waitcnt(0x0F74);       // vmcnt(4)
        } else {
            __builtin_amdgcn_s_waitcnt(0x0F70);       // vmcnt(0)
        }
        __syncthreads();

        shortx8 af[4], bf[4];
#pragma unroll
        for (int i = 0; i < 4; i++)
            af[i] = *(const shortx8*)(As[cur] + (wm + i * 16 + fr) * TKK + rswz);
#pragma unroll
        for (int j = 0; j < 4; j++)
            bf[j] = *(const shortx8*)(Bs[cur] + (wn + j * 16 + fr) * TKK + rswz);
#pragma unroll
        for (int i = 0; i < 4; i++)
#pragma unroll
            for (int j = 0; j < 4; j++)
                acc[i][j] = __builtin_amdgcn_mfma_f32_16x16x32_bf16(af[i], bf[j], acc[i][j], 0, 0, 0);
        __syncthreads();
    }
#undef GEMM_STAGE

#pragma unroll
    for (int i = 0; i < 4; i++) {
#pragma unroll
        for (int j = 0; j < 4; j++) {
            int col = bn + wn + j * 16 + fr;
            float bv = bias[col];
#pragma unroll
            for (int rr = 0; rr < 4; rr++) {
                int row = bm + wm + i * 16 + fq * 4 + rr;
                if (row < M) C[(size_t)row * ldc + cShift + col] = f2b(acc[i][j][rr] + bv);
            }
        }
    }
}

// ---------------------------------------------------------------------------
// CSR build
// ---------------------------------------------------------------------------
__global__ void count_deg(const int* __restrict__ dst, int* __restrict__ deg,
                          int N, int E) {
    int i = blockIdx.x * blockDim.x + threadIdx.x;
    if (i >= 2 * E) return;
    int et = i / E, e = i - et * E;
    int d = dst[(size_t)et * E + e];
    atomicAdd(&deg[(1 - et) * N + d], 1);
}

// --- 3-stage fully-parallel exclusive scan ---
__launch_bounds__(256)
__global__ void scan_blocks(int* __restrict__ deg, int* __restrict__ bsum, int n) {
    __shared__ int wsum[4];
    int tid = threadIdx.x, lane = tid & 63, w = tid >> 6;
    int i = blockIdx.x * 256 + tid;
    int v = (i < n) ? deg[i] : 0;
    int x = v;
#pragma unroll
    for (int off = 1; off < 64; off <<= 1) {
        int y = __shfl_up(x, off);
        if (lane >= off) x += y;
    }
    if (lane == 63) wsum[w] = x;
    __syncthreads();
    int add = 0;
    if (w > 0) add += wsum[0];
    if (w > 1) add += wsum[1];
    if (w > 2) add += wsum[2];
    int incl = x + add;
    if (i < n) deg[i] = incl - v;          // exclusive within block
    if (tid == 255) bsum[blockIdx.x] = incl;  // block total
}

__launch_bounds__(512)
__global__ void scan_tops(int* __restrict__ bsum, int* __restrict__ row_ptr,
                          int nb, int n) {
    __shared__ int wsum[8];
    int tid = threadIdx.x, lane = tid & 63, w = tid >> 6;
    int v = (tid < nb) ? bsum[tid] : 0;
    int x = v;
#pragma unroll
    for (int off = 1; off < 64; off <<= 1) {
        int y = __shfl_up(x, off);
        if (lane >= off) x += y;
    }
    if (lane == 63) wsum[w] = x;
    __syncthreads();
    int add = 0;
    for (int j = 0; j < w; j++) add += wsum[j];
    int incl = x + add;
    if (tid < nb) bsum[tid] = incl - v;    // exclusive block offsets
    if (tid == nb - 1) row_ptr[n] = incl;  // grand total
}

__launch_bounds__(256)
__global__ void scan_apply(const int* __restrict__ excl, const int* __restrict__ bsum,
                           int* __restrict__ row_ptr, int* __restrict__ cursor, int n) {
    int i = blockIdx.x * 256 + threadIdx.x;
    if (i >= n) return;
    int e = excl[i] + bsum[blockIdx.x];
    row_ptr[i] = e;
    cursor[i] = e;
}

__global__ void fill_edges(const int* __restrict__ src, const int* __restrict__ dst,
                           int* __restrict__ cursor, int* __restrict__ ebuf,
                           int N, int E) {
    int i = blockIdx.x * blockDim.x + threadIdx.x;
    if (i >= 2 * E) return;
    int et = i / E, e = i - et * E;
    int d = dst[(size_t)et * E + e];
    int s = src[(size_t)et * E + e];
    int pos = atomicAdd(&cursor[(1 - et) * N + d], 1);
    ebuf[pos] = s;
}

// ---------------------------------------------------------------------------
// Node-centric aggregation; split per dst-type into two dispatches (wbase).
// One wave per destination node, two 32-lane halves on even/odd CSR edges,
// depth-2 register pipeline, packed-f32 math. ~Structural floor (~3.7 TB/s
// random 1KB fetches from a 102MB set: L2-thrash, L3-resident).
// ---------------------------------------------------------------------------
__launch_bounds__(256)
__global__ void node_aggregate(ushort_t* __restrict__ QKV, const float* __restrict__ mu,
                               const int* __restrict__ row_ptr, const int* __restrict__ ebuf,
                               int N, int wbase) {
    int wid = ((blockIdx.x * blockDim.x + threadIdx.x) >> 6) + wbase;
    int lane = threadIdx.x & 63;
    if (wid >= wbase + N) return;
    int dt = (wid >= N) ? 1 : 0;
    int et = 1 - dt;
    int l = lane & 31;
    int half = lane >> 5;
    int h = l >> 2;

    uint4 qu = ((const uint4*)(QKV + (size_t)wid * 768))[l];
    floatx2 q01 = b2x2(qu.x), q23 = b2x2(qu.y), q45 = b2x2(qu.z), q67 = b2x2(qu.w);
    float sc = mu[et * H + h] * 0.17677669529663687f;  // 1/sqrt(32)
    int beg = row_ptr[wid], end = row_ptr[wid + 1];
    const ushort_t* KVb = QKV + (size_t)et * N * 768 + l * 8;

    floatx2 a01 = {0.f, 0.f}, a23 = {0.f, 0.f}, a45 = {0.f, 0.f}, a67 = {0.f, 0.f};
    float ssum = 0.f;

#define AGG_COMPUTE(kk, vv)                                              \
    {                                                                    \
        floatx2 pv = q01 * b2x2(kk.x);                                   \
        pv += q23 * b2x2(kk.y);                                          \
        pv += q45 * b2x2(kk.z);                                          \
        pv += q67 * b2x2(kk.w);                                          \
        float pp = pv.x + pv.y;                                          \
        pp += __shfl_xor(pp, 1);                                         \
        pp += __shfl_xor(pp, 2);                                         \
        float ex = __expf(pp * sc);                                      \
        ssum += ex;                                                      \
        floatx2 e2 = {ex, ex};                                           \
        a01 += e2 * b2x2(vv.x);                                          \
        a23 += e2 * b2x2(vv.y);                                          \
        a45 += e2 * b2x2(vv.z);                                          \
        a67 += e2 * b2x2(vv.w);                                          \
    }

    int p = beg + half;
    uint4 kA = {}, vA = {}, kB = {}, vB = {};
    int sC = 0, sD = 0;
    if (p < end) {
        int sA = ebuf[p];
        const ushort_t* r0 = KVb + (size_t)sA * 768;
        kA = *(const uint4*)(r0 + 256);
        vA = *(const uint4*)(r0 + 512);
        sC = (p + 4 < end) ? ebuf[p + 4] : sA;
    }
    if (p + 2 < end) {
        int sB = ebuf[p + 2];
        const ushort_t* r1 = KVb + (size_t)sB * 768;
        kB = *(const uint4*)(r1 + 256);
        vB = *(const uint4*)(r1 + 512);
        sD = (p + 6 < end) ? ebuf[p + 6] : sB;
    }
    while (p < end) {
        uint4 nk = kA, nv = vA;
        int sE = sC;
        if (p + 4 < end) {
            const ushort_t* rr = KVb + (size_t)sC * 768;
            nk = *(const uint4*)(rr + 256);
            nv = *(const uint4*)(rr + 512);
            if (p + 8 < end) sE = ebuf[p + 8];
        }
        AGG_COMPUTE(kA, vA);
        kA = nk; vA = nv; sC = sE;
        p += 2;
        if (p >= end) break;
        nk = kB; nv = vB; sE = sD;
        if (p + 4 < end) {
            const ushort_t* rr = KVb + (size_t)sD * 768;
            nk = *(const uint4*)(rr + 256);
            nv = *(const uint4*)(rr + 512);
            if (p + 8 < end) sE = ebuf[p + 8];
        }
        AGG_COMPUTE(kB, vB);
        kB = nk; vB = nv; sD = sE;
        p += 2;
    }
#undef AGG_COMPUTE

    ssum += __shfl_xor(ssum, 32);
    a01.x += __shfl_xor(a01.x, 32); a01.y += __shfl_xor(a01.y, 32);
    a23.x += __shfl_xor(a23.x, 32); a23.y += __shfl_xor(a23.y, 32);
    a45.x += __shfl_xor(a45.x, 32); a45.y += __shfl_xor(a45.y, 32);
    a67.x += __shfl_xor(a67.x, 32); a67.y += __shfl_xor(a67.y, 32);
    float r = (ssum > 0.f) ? 1.0f / ssum : 0.0f;
    if (half == 0) {
        ushortx8 hv;
        hv[0] = f2b(a01.x * r); hv[1] = f2b(a01.y * r);
        hv[2] = f2b(a23.x * r); hv[3] = f2b(a23.y * r);
        hv[4] = f2b(a45.x * r); hv[5] = f2b(a45.y * r);
        hv[6] = f2b(a67.x * r); hv[7] = f2b(a67.y * r);
        ((ushortx8*)(QKV + (size_t)wid * 768))[l] = hv;
    }
}

// ---------------------------------------------------------------------------
// out = LN(alpha*trans + (1-alpha)*feats_bf16) * ln_w + ln_b.
// Wave per row. trans lives in the K-section of QKV (stride 768);
// feats read as bf16 from featsb.
// ---------------------------------------------------------------------------
__launch_bounds__(256)
__global__ void skip_ln(const ushort_t* __restrict__ trans, const ushort_t* __restrict__ featsb,
                        const float* __restrict__ lnw, const float* __restrict__ lnb,
                        const float* __restrict__ skip, float* __restrict__ out, int N) {
    int wid = (blockIdx.x * blockDim.x + threadIdx.x) >> 6;
    int lane = threadIdx.x & 63;
    if (wid >= 2 * N) return;
    int t = (wid >= N) ? 1 : 0;
    float alpha = 1.0f / (1.0f + __expf(-skip[t]));
    float beta = 1.0f - alpha;
    ushort4 tu = ((const ushort4*)(trans + (size_t)wid * 768))[lane];
    ushort4 fu = ((const ushort4*)(featsb + (size_t)wid * D))[lane];
    float x0 = alpha * b2f(tu.x) + beta * b2f(fu.x);
    float x1 = alpha * b2f(tu.y) + beta * b2f(fu.y);
    float x2 = alpha * b2f(tu.z) + beta * b2f(fu.z);
    float x3 = alpha * b2f(tu.w) + beta * b2f(fu.w);
    float s  = x0 + x1 + x2 + x3;
    float sq = x0 * x0 + x1 * x1 + x2 * x2 + x3 * x3;
#pragma unroll
    for (int off = 1; off < 64; off <<= 1) {
        s  += __shfl_xor(s,  off);
        sq += __shfl_xor(sq, off);
    }
    float mean = s * (1.0f / 256.0f);
    float var  = sq * (1.0f / 256.0f) - mean * mean;
    float r = rsqrtf(var + 1e-5f);
    float4 w4 = ((const float4*)(lnw + t * D))[lane];
    float4 b4 = ((const float4*)(lnb + t * D))[lane];
    float4 o;
    o.x = (x0 - mean) * r * w4.x + b4.x;
    o.y = (x1 - mean) * r * w4.y + b4.y;
    o.z = (x2 - mean) * r * w4.z + b4.z;
    o.w = (x3 - mean) * r * w4.w + b4.w;
    ((float4*)(out + (size_t)wid * D))[lane] = o;
}

extern "C" void kernel_launch(void* const* d_in, const int* in_sizes, int n_in,
                              void* d_out, int out_size, void* d_ws, size_t ws_size,
                              hipStream_t stream) {
    const float* feats = (const float*)d_in[0];
    const float* Wk    = (const float*)d_in[1];
    const float* bk    = (const float*)d_in[2];
    const float* Wq    = (const float*)d_in[3];
    const float* bq    = (const float*)d_in[4];
    const float* Wv    = (const float*)d_in[5];
    const float* bv    = (const float*)d_in[6];
    const float* Wa    = (const float*)d_in[7];
    const float* ba    = (const float*)d_in[8];
    const float* ln_w  = (const float*)d_in[9];
    const float* ln_b  = (const float*)d_in[10];
    const float* skip  = (const float*)d_in[11];
    const float* mu    = (const float*)d_in[12];
    const float* w_att = (const float*)d_in[13];
    const float* w_msg = (const float*)d_in[14];
    const int*   src   = (const int*)d_in[15];
    const int*   dst   = (const int*)d_in[16];
    float* out = (float*)d_out;

    const int N = in_sizes[0] / (2 * D);
    const int E = in_sizes[15] / 2;
    const int NN = 2 * N;
    const size_t ND2 = 2 * (size_t)N * D;     // 25.6M elems

    // Workspace layout (float units). ~212 MB total.
    float* ws = (float*)d_ws;
    size_t off = 0;
    float* Wkc  = ws + off; off += 2 * (size_t)D * D;
    float* Wvc  = ws + off; off += 2 * (size_t)D * D;
    float* bkc  = ws + off; off += 2 * D;
    float* bvc  = ws + off; off += 2 * D;
    float* bias_all = ws + off; off += 2 * 768;
    ushort_t* WT_all = (ushort_t*)(ws + off); off += 2 * 768 * 256 / 2;
    ushort_t* WaT    = (ushort_t*)(ws + off); off += 2 * 256 * 256 / 2;
    ushort_t* featsb = (ushort_t*)(ws + off); off += ND2 / 2;   // bf16 feats (stays intact)
    ushort_t* QKV    = (ushort_t*)(ws + off); off += 2 * (size_t)N * 768 / 2;
    int* deg     = (int*)(ws + off); off += NN;
    int* row_ptr = (int*)(ws + off); off += NN + 1;
    int* cursor  = (int*)(ws + off); off += NN + 1;
    int* ebuf    = (int*)(ws + off); off += 2 * (size_t)E;
    int* bsum    = (int*)(ws + off); off += 512;

    const int nb = (NN + 255) / 256;          // scan blocks (<=512 required)

    // --- CSR build ---
    zero_int<<<(NN + 255) / 256, 256, 0, stream>>>(deg, NN);
    count_deg<<<(2 * E + 255) / 256, 256, 0, stream>>>(dst, deg, N, E);
    scan_blocks<<<nb, 256, 0, stream>>>(deg, bsum, NN);
    scan_tops<<<1, 512, 0, stream>>>(bsum, row_ptr, nb, NN);
    scan_apply<<<nb, 256, 0, stream>>>(deg, bsum, row_ptr, cursor, NN);
    fill_edges<<<(2 * E + 255) / 256, 256, 0, stream>>>(src, dst, cursor, ebuf, N, E);

    // --- weight prep ---
    fold_weights<<<dim3(D, 2, 2), 256, 0, stream>>>(Wk, bk, Wv, bv, w_att, w_msg,
                                                    Wkc, bkc, Wvc, bvc);
    pack_weights<<<(2 * 768 * 256 + 2 * 256 * 256 + 255) / 256, 256, 0, stream>>>(
        Wq, bq, Wkc, bkc, Wvc, bvc, Wa, WT_all, WaT, bias_all);

    // --- feats -> bf16 ---
    cvt_bf16<<<(unsigned)((ND2 / 4 + 255) / 256), 256, 0, stream>>>(feats, featsb, ND2 / 4);

    // --- fused Q|K|V GEMM, both ntypes (grid.z): (N x 256) @ (256 x 768) ---
    dim3 qkv_grid((N + TM - 1) / TM, 768 / TN, 2);
    gemm_mfma<<<qkv_grid, 256, 0, stream>>>(featsb, D, (size_t)N * D,
                                            WT_all, (size_t)768 * 256,
                                            bias_all, 768,
                                            QKV, 768, (size_t)N * 768, 0, N);

    // --- attention aggregation, split per dst-type ---
    node_aggregate<<<((size_t)N * 64 + 255) / 256, 256, 0, stream>>>(QKV, mu, row_ptr, ebuf, N, 0);
    node_aggregate<<<((size_t)N * 64 + 255) / 256, 256, 0, stream>>>(QKV, mu, row_ptr, ebuf, N, N);

    // --- trans = H @ Wa + ba -> K-section of QKV (cols 256..511, bf16) ---
    // (A reads cols 0..255 of the same rows; writes are to disjoint cols.)
    dim3 tr_grid((N + TM - 1) / TM, 256 / TN, 2);
    gemm_mfma<<<tr_grid, 256, 0, stream>>>(QKV, 768, (size_t)N * 768,
                                           WaT, (size_t)256 * 256,
                                           ba, 256,
                                           QKV, 768, (size_t)N * 768, 256, N);

    skip_ln<<<(NN * 64 + 255) / 256, 256, 0, stream>>>(QKV + 256, featsb,
                                                       ln_w, ln_b, skip, out, N);
}

// Round 7
// 626.172 us; speedup vs baseline: 1.0146x; 1.0146x over previous
//
#include <hip/hip_runtime.h>
#include <hip/hip_bf16.h>

#define D 256
#define H 8
#define DK 32

typedef unsigned short ushort_t;
typedef unsigned int uint_t;
typedef __attribute__((ext_vector_type(4))) float floatx4;
typedef __attribute__((ext_vector_type(2))) float floatx2;
typedef __attribute__((ext_vector_type(8))) short shortx8;
typedef __attribute__((ext_vector_type(8))) unsigned short ushortx8;

typedef __attribute__((address_space(3))) void lds_void_t;
typedef const __attribute__((address_space(1))) void gbl_void_t;

__device__ __forceinline__ float b2f(ushort_t u) {
    return __uint_as_float(((uint_t)u) << 16);
}
__device__ __forceinline__ floatx2 b2x2(uint_t u) {
    floatx2 r;
    r.x = __uint_as_float(u << 16);
    r.y = __uint_as_float(u & 0xffff0000u);
    return r;
}
__device__ __forceinline__ ushort_t f2b(float f) {
    uint_t u = __float_as_uint(f);
    uint_t r = (u + 0x7FFFu + ((u >> 16) & 1u)) >> 16;   // RNE
    return (ushort_t)r;
}
__device__ __forceinline__ void async_cp16(const void* g, void* l) {
    __builtin_amdgcn_global_load_lds((gbl_void_t*)g, (lds_void_t*)l, 16, 0, 0);
}

// ---------------------------------------------------------------------------
// feats fp32 -> bf16 (vectorized)
// ---------------------------------------------------------------------------
__global__ void cvt_bf16(const float* __restrict__ in, ushort_t* __restrict__ out, size_t n4) {
    size_t i = (size_t)blockIdx.x * blockDim.x + threadIdx.x;
    if (i >= n4) return;
    float4 v = ((const float4*)in)[i];
    ushort4 o;
    o.x = f2b(v.x); o.y = f2b(v.y); o.z = f2b(v.z); o.w = f2b(v.w);
    ((ushort4*)out)[i] = o;
}

__global__ void zero_int(int* __restrict__ p, int n) {
    int i = blockIdx.x * blockDim.x + threadIdx.x;
    if (i < n) p[i] = 0;
}

// ---------------------------------------------------------------------------
// Fold per-head w_att/w_msg into Wk/Wv (fp32, D x D) and biases.
// ---------------------------------------------------------------------------
__global__ void fold_weights(const float* __restrict__ Wk, const float* __restrict__ bk,
                             const float* __restrict__ Wv, const float* __restrict__ bv,
                             const float* __restrict__ w_att, const float* __restrict__ w_msg,
                             float* __restrict__ Wkc, float* __restrict__ bkc,
                             float* __restrict__ Wvc, float* __restrict__ bvc) {
    int r = blockIdx.x, et = blockIdx.y, which = blockIdx.z;
    int tid = threadIdx.x;
    const float* Wsrc = (which ? Wv : Wk) + (size_t)et * D * D + (size_t)r * D;
    const float* wt   = (which ? w_msg : w_att) + (size_t)et * H * DK * DK;
    float* Wdst = (which ? Wvc : Wkc) + (size_t)et * D * D;
    __shared__ float wrow[D];
    wrow[tid] = Wsrc[tid];
    __syncthreads();
    int h = tid >> 5, j = tid & 31;
    const float* wth = wt + h * DK * DK;
    float acc = 0.f;
#pragma unroll 8
    for (int i = 0; i < DK; i++) acc += wrow[h * 32 + i] * wth[i * 32 + j];
    Wdst[(size_t)r * D + tid] = acc;
    if (r == 0) {
        const float* bsrc = (which ? bv : bk) + et * D;
        float* bdst = (which ? bvc : bkc) + et * D;
        float bacc = 0.f;
#pragma unroll 8
        for (int i = 0; i < DK; i++) bacc += bsrc[h * 32 + i] * wth[i * 32 + j];
        bdst[tid] = bacc;
    }
}

// ---------------------------------------------------------------------------
// Pack transposed bf16 weights:
//   WT_all[t][n][k], n in [0,768): {Wq | Wkc | Wvc}[t][k][n%256]
//   WaT[t][n][k] = Wa[t][k][n]
//   bias_all[t][n] = {bq | bkc | bvc}
// ---------------------------------------------------------------------------
__global__ void pack_weights(const float* __restrict__ Wq, const float* __restrict__ bq,
                             const float* __restrict__ Wkc, const float* __restrict__ bkc,
                             const float* __restrict__ Wvc, const float* __restrict__ bvc,
                             const float* __restrict__ Wa,
                             ushort_t* __restrict__ WT_all, ushort_t* __restrict__ WaT,
                             float* __restrict__ bias_all) {
    int idx = blockIdx.x * blockDim.x + threadIdx.x;
    const int NW = 2 * 768 * 256;
    if (idx < NW) {
        int t = idx / (768 * 256);
        int rem = idx - t * 768 * 256;
        int n = rem >> 8, k = rem & 255;
        int sec = n >> 8, nn = n & 255;
        const float* W = (sec == 0) ? Wq : (sec == 1) ? Wkc : Wvc;
        WT_all[idx] = f2b(W[(size_t)t * D * D + (size_t)k * D + nn]);
    } else if (idx < NW + 2 * 256 * 256) {
        int r = idx - NW;
        int t = r / (256 * 256);
        int rem = r - t * 256 * 256;
        int n = rem >> 8, k = rem & 255;
        WaT[r] = f2b(Wa[(size_t)t * D * D + (size_t)k * D + n]);
    }
    if (idx < 2 * 768) {
        int t = idx / 768, n = idx % 768;
        int sec = n >> 8, nn = n & 255;
        const float* b = (sec == 0) ? bq : (sec == 1) ? bkc : bvc;
        bias_all[idx] = b[t * D + nn];
    }
}

// ---------------------------------------------------------------------------
// bf16 MFMA GEMM: C(M x Ncols) = A(M x 256) @ BT^T + bias, bf16 out at
// col offset cShift, stride ldc. blockIdx.z = type. 128x128 tile, TKK=32,
// DEPTH-2 staging: 3 LDS buffers; step s issues stage(s+2) and waits
// vmcnt(8) (8 loads stay in flight across the barrier; never 0 mid-loop).
// Issue-to-wait distance = 2 full K-steps, covering the ~600-900cy L3-class
// load latency that depth-1 (R4-R6, vmcnt(4)) left exposed each step.
// Rotation hazard: buf t%3 re-staged at step t+1 AFTER step t's 2nd barrier,
// which all readers of that buffer passed. No LDS swizzle: R6 proved
// conflicts (4.8M) are off the critical path and the swizzle's VGPR cost
// (64->68) dropped occupancy 39->28.6%.
// XCD-chunked bijective remap (m204), col-tile fastest for A L2 reuse.
// ---------------------------------------------------------------------------
#define TM 128
#define TN 128
#define TKK 32
__launch_bounds__(256)
__global__ void gemm_mfma(const ushort_t* __restrict__ A0, int lda, size_t aStr,
                          const ushort_t* __restrict__ BT0, size_t bStr,
                          const float* __restrict__ bias0, int biasStr,
                          ushort_t* __restrict__ C0, int ldc, size_t cStr,
                          int cShift, int M) {
    __shared__ ushort_t As[3][TM * TKK];   // 3 x 8 KB
    __shared__ ushort_t Bs[3][TN * TKK];   // 3 x 8 KB
    int tid = threadIdx.x;
    int w = tid >> 6, lane = tid & 63;
    int t = blockIdx.z;
    const ushort_t* A  = A0 + (size_t)t * aStr;
    const ushort_t* BT = BT0 + (size_t)t * bStr;
    const float* bias  = bias0 + (size_t)t * biasStr;
    ushort_t* C        = C0 + (size_t)t * cStr;

    // --- XCD-chunked bijective swizzle, col-tile fastest ---
    int nwg  = gridDim.x * gridDim.y;
    int orig = blockIdx.y * gridDim.x + blockIdx.x;
    int q = nwg >> 3, r = nwg & 7;
    int xcd = orig & 7, loc = orig >> 3;
    int wgid = (xcd < r ? xcd * (q + 1) : r * (q + 1) + (xcd - r) * q) + loc;
    int ncol = gridDim.y;
    int rowt = wgid / ncol;
    int colt = wgid - rowt * ncol;
    int bm = rowt * TM;
    int bn = colt * TN;

    int wm = (w & 1) * 64, wn = (w >> 1) * 64;

    floatx4 acc[4][4] = {};

    int srow = lane >> 2;            // 16 rows per cp16 (64 lanes x 16B, 64B rows)
    int scol = (lane & 3) * 8;       // k offset (ushorts)
    int fr = lane & 15, fq = lane >> 4;

#define GEMM_STAGE(b, kc)                                                     \
    {                                                                         \
        _Pragma("unroll")                                                     \
        for (int j = 0; j < 2; j++) {                                         \
            int rr = w * 32 + j * 16;                                         \
            int gr = bm + rr + srow; if (gr >= M) gr = M - 1;                 \
            async_cp16(A + (size_t)gr * lda + (kc) + scol, As[b] + rr * TKK); \
            int gn = bn + rr + srow;                                          \
            async_cp16(BT + (size_t)gn * 256 + (kc) + scol, Bs[b] + rr * TKK);\
        }                                                                     \
    }

    GEMM_STAGE(0, 0);
    GEMM_STAGE(1, TKK);
#pragma unroll
    for (int s = 0; s < 8; s++) {
        int cur = s % 3;
        if (s < 6) {
            GEMM_STAGE((s + 2) % 3, (s + 2) * TKK);
            __builtin_amdgcn_s_waitcnt(0x0F78);       // vmcnt(8): stage(s) done, 8 in flight
        } else if (s == 6) {
            __builtin_amdgcn_s_waitcnt(0x0F74);       // vmcnt(4): stage(6) done
        } else {
            __builtin_amdgcn_s_waitcnt(0x0F70);       // vmcnt(0): stage(7) done
        }
        __syncthreads();

        shortx8 af[4], bf[4];
#pragma unroll
        for (int i = 0; i < 4; i++)
            af[i] = *(const shortx8*)(As[cur] + (wm + i * 16 + fr) * TKK + fq * 8);
#pragma unroll
        for (int j = 0; j < 4; j++)
            bf[j] = *(const shortx8*)(Bs[cur] + (wn + j * 16 + fr) * TKK + fq * 8);
#pragma unroll
        for (int i = 0; i < 4; i++)
#pragma unroll
            for (int j = 0; j < 4; j++)
                acc[i][j] = __builtin_amdgcn_mfma_f32_16x16x32_bf16(af[i], bf[j], acc[i][j], 0, 0, 0);
        __syncthreads();   // all waves done reading buf 'cur' before it is re-staged
    }
#undef GEMM_STAGE

#pragma unroll
    for (int i = 0; i < 4; i++) {
#pragma unroll
        for (int j = 0; j < 4; j++) {
            int col = bn + wn + j * 16 + fr;
            float bv = bias[col];
#pragma unroll
            for (int rr = 0; rr < 4; rr++) {
                int row = bm + wm + i * 16 + fq * 4 + rr;
                if (row < M) C[(size_t)row * ldc + cShift + col] = f2b(acc[i][j][rr] + bv);
            }
        }
    }
}

// ---------------------------------------------------------------------------
// CSR build
// ---------------------------------------------------------------------------
__global__ void count_deg(const int* __restrict__ dst, int* __restrict__ deg,
                          int N, int E) {
    int i = blockIdx.x * blockDim.x + threadIdx.x;
    if (i >= 2 * E) return;
    int et = i / E, e = i - et * E;
    int d = dst[(size_t)et * E + e];
    atomicAdd(&deg[(1 - et) * N + d], 1);
}

// --- 3-stage fully-parallel exclusive scan ---
__launch_bounds__(256)
__global__ void scan_blocks(int* __restrict__ deg, int* __restrict__ bsum, int n) {
    __shared__ int wsum[4];
    int tid = threadIdx.x, lane = tid & 63, w = tid >> 6;
    int i = blockIdx.x * 256 + tid;
    int v = (i < n) ? deg[i] : 0;
    int x = v;
#pragma unroll
    for (int off = 1; off < 64; off <<= 1) {
        int y = __shfl_up(x, off);
        if (lane >= off) x += y;
    }
    if (lane == 63) wsum[w] = x;
    __syncthreads();
    int add = 0;
    if (w > 0) add += wsum[0];
    if (w > 1) add += wsum[1];
    if (w > 2) add += wsum[2];
    int incl = x + add;
    if (i < n) deg[i] = incl - v;          // exclusive within block
    if (tid == 255) bsum[blockIdx.x] = incl;  // block total
}

__launch_bounds__(512)
__global__ void scan_tops(int* __restrict__ bsum, int* __restrict__ row_ptr,
                          int nb, int n) {
    __shared__ int wsum[8];
    int tid = threadIdx.x, lane = tid & 63, w = tid >> 6;
    int v = (tid < nb) ? bsum[tid] : 0;
    int x = v;
#pragma unroll
    for (int off = 1; off < 64; off <<= 1) {
        int y = __shfl_up(x, off);
        if (lane >= off) x += y;
    }
    if (lane == 63) wsum[w] = x;
    __syncthreads();
    int add = 0;
    for (int j = 0; j < w; j++) add += wsum[j];
    int incl = x + add;
    if (tid < nb) bsum[tid] = incl - v;    // exclusive block offsets
    if (tid == nb - 1) row_ptr[n] = incl;  // grand total
}

__launch_bounds__(256)
__global__ void scan_apply(const int* __restrict__ excl, const int* __restrict__ bsum,
                           int* __restrict__ row_ptr, int* __restrict__ cursor, int n) {
    int i = blockIdx.x * 256 + threadIdx.x;
    if (i >= n) return;
    int e = excl[i] + bsum[blockIdx.x];
    row_ptr[i] = e;
    cursor[i] = e;
}

__global__ void fill_edges(const int* __restrict__ src, const int* __restrict__ dst,
                           int* __restrict__ cursor, int* __restrict__ ebuf,
                           int N, int E) {
    int i = blockIdx.x * blockDim.x + threadIdx.x;
    if (i >= 2 * E) return;
    int et = i / E, e = i - et * E;
    int d = dst[(size_t)et * E + e];
    int s = src[(size_t)et * E + e];
    int pos = atomicAdd(&cursor[(1 - et) * N + d], 1);
    ebuf[pos] = s;
}

// ---------------------------------------------------------------------------
// Node-centric aggregation (single dispatch over 2N nodes — split reverted,
// it cost ~10us of tail/launch with no perf benefit).
// One wave per destination node, two 32-lane halves on even/odd CSR edges,
// depth-2 register pipeline, packed-f32 math. ~Structural floor (~3.7 TB/s
// random 1KB fetches from a 102MB set: L2-thrash, L3-resident).
// ---------------------------------------------------------------------------
__launch_bounds__(256)
__global__ void node_aggregate(ushort_t* __restrict__ QKV, const float* __restrict__ mu,
                               const int* __restrict__ row_ptr, const int* __restrict__ ebuf,
                               int N) {
    int wid = (blockIdx.x * blockDim.x + threadIdx.x) >> 6;
    int lane = threadIdx.x & 63;
    if (wid >= 2 * N) return;
    int dt = (wid >= N) ? 1 : 0;
    int et = 1 - dt;
    int l = lane & 31;
    int half = lane >> 5;
    int h = l >> 2;

    uint4 qu = ((const uint4*)(QKV + (size_t)wid * 768))[l];
    floatx2 q01 = b2x2(qu.x), q23 = b2x2(qu.y), q45 = b2x2(qu.z), q67 = b2x2(qu.w);
    float sc = mu[et * H + h] * 0.17677669529663687f;  // 1/sqrt(32)
    int beg = row_ptr[wid], end = row_ptr[wid + 1];
    const ushort_t* KVb = QKV + (size_t)et * N * 768 + l * 8;

    floatx2 a01 = {0.f, 0.f}, a23 = {0.f, 0.f}, a45 = {0.f, 0.f}, a67 = {0.f, 0.f};
    float ssum = 0.f;

#define AGG_COMPUTE(kk, vv)                                              \
    {                                                                    \
        floatx2 pv = q01 * b2x2(kk.x);                                   \
        pv += q23 * b2x2(kk.y);                                          \
        pv += q45 * b2x2(kk.z);                                          \
        pv += q67 * b2x2(kk.w);                                          \
        float pp = pv.x + pv.y;                                          \
        pp += __shfl_xor(pp, 1);                                         \
        pp += __shfl_xor(pp, 2);                                         \
        float ex = __expf(pp * sc);                                      \
        ssum += ex;                                                      \
        floatx2 e2 = {ex, ex};                                           \
        a01 += e2 * b2x2(vv.x);                                          \
        a23 += e2 * b2x2(vv.y);                                          \
        a45 += e2 * b2x2(vv.z);                                          \
        a67 += e2 * b2x2(vv.w);                                          \
    }

    int p = beg + half;
    uint4 kA = {}, vA = {}, kB = {}, vB = {};
    int sC = 0, sD = 0;
    if (p < end) {
        int sA = ebuf[p];
        const ushort_t* r0 = KVb + (size_t)sA * 768;
        kA = *(const uint4*)(r0 + 256);
        vA = *(const uint4*)(r0 + 512);
        sC = (p + 4 < end) ? ebuf[p + 4] : sA;
    }
    if (p + 2 < end) {
        int sB = ebuf[p + 2];
        const ushort_t* r1 = KVb + (size_t)sB * 768;
        kB = *(const uint4*)(r1 + 256);
        vB = *(const uint4*)(r1 + 512);
        sD = (p + 6 < end) ? ebuf[p + 6] : sB;
    }
    while (p < end) {
        uint4 nk = kA, nv = vA;
        int sE = sC;
        if (p + 4 < end) {
            const ushort_t* rr = KVb + (size_t)sC * 768;
            nk = *(const uint4*)(rr + 256);
            nv = *(const uint4*)(rr + 512);
            if (p + 8 < end) sE = ebuf[p + 8];
        }
        AGG_COMPUTE(kA, vA);
        kA = nk; vA = nv; sC = sE;
        p += 2;
        if (p >= end) break;
        nk = kB; nv = vB; sE = sD;
        if (p + 4 < end) {
            const ushort_t* rr = KVb + (size_t)sD * 768;
            nk = *(const uint4*)(rr + 256);
            nv = *(const uint4*)(rr + 512);
            if (p + 8 < end) sE = ebuf[p + 8];
        }
        AGG_COMPUTE(kB, vB);
        kB = nk; vB = nv; sD = sE;
        p += 2;
    }
#undef AGG_COMPUTE

    ssum += __shfl_xor(ssum, 32);
    a01.x += __shfl_xor(a01.x, 32); a01.y += __shfl_xor(a01.y, 32);
    a23.x += __shfl_xor(a23.x, 32); a23.y += __shfl_xor(a23.y, 32);
    a45.x += __shfl_xor(a45.x, 32); a45.y += __shfl_xor(a45.y, 32);
    a67.x += __shfl_xor(a67.x, 32); a67.y += __shfl_xor(a67.y, 32);
    float r = (ssum > 0.f) ? 1.0f / ssum : 0.0f;
    if (half == 0) {
        ushortx8 hv;
        hv[0] = f2b(a01.x * r); hv[1] = f2b(a01.y * r);
        hv[2] = f2b(a23.x * r); hv[3] = f2b(a23.y * r);
        hv[4] = f2b(a45.x * r); hv[5] = f2b(a45.y * r);
        hv[6] = f2b(a67.x * r); hv[7] = f2b(a67.y * r);
        ((ushortx8*)(QKV + (size_t)wid * 768))[l] = hv;
    }
}

// ---------------------------------------------------------------------------
// out = LN(alpha*trans + (1-alpha)*feats_bf16) * ln_w + ln_b.
// Wave per row. trans lives in the K-section of QKV (stride 768);
// feats read as bf16 from featsb.
// ---------------------------------------------------------------------------
__launch_bounds__(256)
__global__ void skip_ln(const ushort_t* __restrict__ trans, const ushort_t* __restrict__ featsb,
                        const float* __restrict__ lnw, const float* __restrict__ lnb,
                        const float* __restrict__ skip, float* __restrict__ out, int N) {
    int wid = (blockIdx.x * blockDim.x + threadIdx.x) >> 6;
    int lane = threadIdx.x & 63;
    if (wid >= 2 * N) return;
    int t = (wid >= N) ? 1 : 0;
    float alpha = 1.0f / (1.0f + __expf(-skip[t]));
    float beta = 1.0f - alpha;
    ushort4 tu = ((const ushort4*)(trans + (size_t)wid * 768))[lane];
    ushort4 fu = ((const ushort4*)(featsb + (size_t)wid * D))[lane];
    float x0 = alpha * b2f(tu.x) + beta * b2f(fu.x);
    float x1 = alpha * b2f(tu.y) + beta * b2f(fu.y);
    float x2 = alpha * b2f(tu.z) + beta * b2f(fu.z);
    float x3 = alpha * b2f(tu.w) + beta * b2f(fu.w);
    float s  = x0 + x1 + x2 + x3;
    float sq = x0 * x0 + x1 * x1 + x2 * x2 + x3 * x3;
#pragma unroll
    for (int off = 1; off < 64; off <<= 1) {
        s  += __shfl_xor(s,  off);
        sq += __shfl_xor(sq, off);
    }
    float mean = s * (1.0f / 256.0f);
    float var  = sq * (1.0f / 256.0f) - mean * mean;
    float r = rsqrtf(var + 1e-5f);
    float4 w4 = ((const float4*)(lnw + t * D))[lane];
    float4 b4 = ((const float4*)(lnb + t * D))[lane];
    float4 o;
    o.x = (x0 - mean) * r * w4.x + b4.x;
    o.y = (x1 - mean) * r * w4.y + b4.y;
    o.z = (x2 - mean) * r * w4.z + b4.z;
    o.w = (x3 - mean) * r * w4.w + b4.w;
    ((float4*)(out + (size_t)wid * D))[lane] = o;
}

extern "C" void kernel_launch(void* const* d_in, const int* in_sizes, int n_in,
                              void* d_out, int out_size, void* d_ws, size_t ws_size,
                              hipStream_t stream) {
    const float* feats = (const float*)d_in[0];
    const float* Wk    = (const float*)d_in[1];
    const float* bk    = (const float*)d_in[2];
    const float* Wq    = (const float*)d_in[3];
    const float* bq    = (const float*)d_in[4];
    const float* Wv    = (const float*)d_in[5];
    const float* bv    = (const float*)d_in[6];
    const float* Wa    = (const float*)d_in[7];
    const float* ba    = (const float*)d_in[8];
    const float* ln_w  = (const float*)d_in[9];
    const float* ln_b  = (const float*)d_in[10];
    const float* skip  = (const float*)d_in[11];
    const float* mu    = (const float*)d_in[12];
    const float* w_att = (const float*)d_in[13];
    const float* w_msg = (const float*)d_in[14];
    const int*   src   = (const int*)d_in[15];
    const int*   dst   = (const int*)d_in[16];
    float* out = (float*)d_out;

    const int N = in_sizes[0] / (2 * D);
    const int E = in_sizes[15] / 2;
    const int NN = 2 * N;
    const size_t ND2 = 2 * (size_t)N * D;     // 25.6M elems

    // Workspace layout (float units). ~212 MB total.
    float* ws = (float*)d_ws;
    size_t off = 0;
    float* Wkc  = ws + off; off += 2 * (size_t)D * D;
    float* Wvc  = ws + off; off += 2 * (size_t)D * D;
    float* bkc  = ws + off; off += 2 * D;
    float* bvc  = ws + off; off += 2 * D;
    float* bias_all = ws + off; off += 2 * 768;
    ushort_t* WT_all = (ushort_t*)(ws + off); off += 2 * 768 * 256 / 2;
    ushort_t* WaT    = (ushort_t*)(ws + off); off += 2 * 256 * 256 / 2;
    ushort_t* featsb = (ushort_t*)(ws + off); off += ND2 / 2;   // bf16 feats (stays intact)
    ushort_t* QKV    = (ushort_t*)(ws + off); off += 2 * (size_t)N * 768 / 2;
    int* deg     = (int*)(ws + off); off += NN;
    int* row_ptr = (int*)(ws + off); off += NN + 1;
    int* cursor  = (int*)(ws + off); off += NN + 1;
    int* ebuf    = (int*)(ws + off); off += 2 * (size_t)E;
    int* bsum    = (int*)(ws + off); off += 512;

    const int nb = (NN + 255) / 256;          // scan blocks (<=512 required)

    // --- CSR build ---
    zero_int<<<(NN + 255) / 256, 256, 0, stream>>>(deg, NN);
    count_deg<<<(2 * E + 255) / 256, 256, 0, stream>>>(dst, deg, N, E);
    scan_blocks<<<nb, 256, 0, stream>>>(deg, bsum, NN);
    scan_tops<<<1, 512, 0, stream>>>(bsum, row_ptr, nb, NN);
    scan_apply<<<nb, 256, 0, stream>>>(deg, bsum, row_ptr, cursor, NN);
    fill_edges<<<(2 * E + 255) / 256, 256, 0, stream>>>(src, dst, cursor, ebuf, N, E);

    // --- weight prep ---
    fold_weights<<<dim3(D, 2, 2), 256, 0, stream>>>(Wk, bk, Wv, bv, w_att, w_msg,
                                                    Wkc, bkc, Wvc, bvc);
    pack_weights<<<(2 * 768 * 256 + 2 * 256 * 256 + 255) / 256, 256, 0, stream>>>(
        Wq, bq, Wkc, bkc, Wvc, bvc, Wa, WT_all, WaT, bias_all);

    // --- feats -> bf16 ---
    cvt_bf16<<<(unsigned)((ND2 / 4 + 255) / 256), 256, 0, stream>>>(feats, featsb, ND2 / 4);

    // --- fused Q|K|V GEMM, both ntypes (grid.z): (N x 256) @ (256 x 768) ---
    dim3 qkv_grid((N + TM - 1) / TM, 768 / TN, 2);
    gemm_mfma<<<qkv_grid, 256, 0, stream>>>(featsb, D, (size_t)N * D,
                                            WT_all, (size_t)768 * 256,
                                            bias_all, 768,
                                            QKV, 768, (size_t)N * 768, 0, N);

    // --- attention aggregation (H overwrites Q section, bf16) ---
    node_aggregate<<<(NN * 64 + 255) / 256, 256, 0, stream>>>(QKV, mu, row_ptr, ebuf, N);

    // --- trans = H @ Wa + ba -> K-section of QKV (cols 256..511, bf16) ---
    // (A reads cols 0..255 of the same rows; writes are to disjoint cols.)
    dim3 tr_grid((N + TM - 1) / TM, 256 / TN, 2);
    gemm_mfma<<<tr_grid, 256, 0, stream>>>(QKV, 768, (size_t)N * 768,
                                           WaT, (size_t)256 * 256,
                                           ba, 256,
                                           QKV, 768, (size_t)N * 768, 256, N);

    skip_ln<<<(NN * 64 + 255) / 256, 256, 0, stream>>>(QKV + 256, featsb,
                                                       ln_w, ln_b, skip, out, N);
}

// Round 8
// 601.555 us; speedup vs baseline: 1.0561x; 1.0409x over previous
//
#include <hip/hip_runtime.h>
#include <hip/hip_bf16.h>

#define D 256
#define H 8
#define DK 32

typedef unsigned short ushort_t;
typedef unsigned int uint_t;
typedef __attribute__((ext_vector_type(4))) float floatx4;
typedef __attribute__((ext_vector_type(2))) float floatx2;
typedef __attribute__((ext_vector_type(8))) short shortx8;
typedef __attribute__((ext_vector_type(8))) unsigned short ushortx8;

typedef __attribute__((address_space(3))) void lds_void_t;
typedef const __attribute__((address_space(1))) void gbl_void_t;

__device__ __forceinline__ float b2f(ushort_t u) {
    return __uint_as_float(((uint_t)u) << 16);
}
__device__ __forceinline__ floatx2 b2x2(uint_t u) {
    floatx2 r;
    r.x = __uint_as_float(u << 16);
    r.y = __uint_as_float(u & 0xffff0000u);
    return r;
}
__device__ __forceinline__ ushort_t f2b(float f) {
    uint_t u = __float_as_uint(f);
    uint_t r = (u + 0x7FFFu + ((u >> 16) & 1u)) >> 16;   // RNE
    return (ushort_t)r;
}
__device__ __forceinline__ void async_cp16(const void* g, void* l) {
    __builtin_amdgcn_global_load_lds((gbl_void_t*)g, (lds_void_t*)l, 16, 0, 0);
}

// ---------------------------------------------------------------------------
// feats fp32 -> bf16 (vectorized)
// ---------------------------------------------------------------------------
__global__ void cvt_bf16(const float* __restrict__ in, ushort_t* __restrict__ out, size_t n4) {
    size_t i = (size_t)blockIdx.x * blockDim.x + threadIdx.x;
    if (i >= n4) return;
    float4 v = ((const float4*)in)[i];
    ushort4 o;
    o.x = f2b(v.x); o.y = f2b(v.y); o.z = f2b(v.z); o.w = f2b(v.w);
    ((ushort4*)out)[i] = o;
}

__global__ void zero_int(int* __restrict__ p, int n) {
    int i = blockIdx.x * blockDim.x + threadIdx.x;
    if (i < n) p[i] = 0;
}

// ---------------------------------------------------------------------------
// Fold per-head w_att/w_msg into Wk/Wv (fp32, D x D) and biases.
// ---------------------------------------------------------------------------
__global__ void fold_weights(const float* __restrict__ Wk, const float* __restrict__ bk,
                             const float* __restrict__ Wv, const float* __restrict__ bv,
                             const float* __restrict__ w_att, const float* __restrict__ w_msg,
                             float* __restrict__ Wkc, float* __restrict__ bkc,
                             float* __restrict__ Wvc, float* __restrict__ bvc) {
    int r = blockIdx.x, et = blockIdx.y, which = blockIdx.z;
    int tid = threadIdx.x;
    const float* Wsrc = (which ? Wv : Wk) + (size_t)et * D * D + (size_t)r * D;
    const float* wt   = (which ? w_msg : w_att) + (size_t)et * H * DK * DK;
    float* Wdst = (which ? Wvc : Wkc) + (size_t)et * D * D;
    __shared__ float wrow[D];
    wrow[tid] = Wsrc[tid];
    __syncthreads();
    int h = tid >> 5, j = tid & 31;
    const float* wth = wt + h * DK * DK;
    float acc = 0.f;
#pragma unroll 8
    for (int i = 0; i < DK; i++) acc += wrow[h * 32 + i] * wth[i * 32 + j];
    Wdst[(size_t)r * D + tid] = acc;
    if (r == 0) {
        const float* bsrc = (which ? bv : bk) + et * D;
        float* bdst = (which ? bvc : bkc) + et * D;
        float bacc = 0.f;
#pragma unroll 8
        for (int i = 0; i < DK; i++) bacc += bsrc[h * 32 + i] * wth[i * 32 + j];
        bdst[tid] = bacc;
    }
}

// ---------------------------------------------------------------------------
// Pack transposed bf16 weights:
//   WT_all[t][n][k], n in [0,768): {Wq | Wkc | Wvc}[t][k][n%256]
//   WaT[t][n][k] = Wa[t][k][n]
//   bias_all[t][n] = {bq | bkc | bvc}
// ---------------------------------------------------------------------------
__global__ void pack_weights(const float* __restrict__ Wq, const float* __restrict__ bq,
                             const float* __restrict__ Wkc, const float* __restrict__ bkc,
                             const float* __restrict__ Wvc, const float* __restrict__ bvc,
                             const float* __restrict__ Wa,
                             ushort_t* __restrict__ WT_all, ushort_t* __restrict__ WaT,
                             float* __restrict__ bias_all) {
    int idx = blockIdx.x * blockDim.x + threadIdx.x;
    const int NW = 2 * 768 * 256;
    if (idx < NW) {
        int t = idx / (768 * 256);
        int rem = idx - t * 768 * 256;
        int n = rem >> 8, k = rem & 255;
        int sec = n >> 8, nn = n & 255;
        const float* W = (sec == 0) ? Wq : (sec == 1) ? Wkc : Wvc;
        WT_all[idx] = f2b(W[(size_t)t * D * D + (size_t)k * D + nn]);
    } else if (idx < NW + 2 * 256 * 256) {
        int r = idx - NW;
        int t = r / (256 * 256);
        int rem = r - t * 256 * 256;
        int n = rem >> 8, k = rem & 255;
        WaT[r] = f2b(Wa[(size_t)t * D * D + (size_t)k * D + n]);
    }
    if (idx < 2 * 768) {
        int t = idx / 768, n = idx % 768;
        int sec = n >> 8, nn = n & 255;
        const float* b = (sec == 0) ? bq : (sec == 1) ? bkc : bvc;
        bias_all[idx] = b[t * D + nn];
    }
}

// ---------------------------------------------------------------------------
// bf16 MFMA GEMM (R4-proven best): C(M x Ncols) = A(M x 256) @ BT^T + bias,
// bf16 out at col offset cShift, stride ldc. blockIdx.z = type. 128x128
// tile, TKK=32, depth-1 2-phase double-buffer, counted vmcnt(4) mid-loop.
// Occupancy > ILP on this workload: depth-2 (48KB LDS, R7) and LDS swizzle
// (+4 VGPR, R6) both regressed by cutting blocks/CU. Do not re-add.
// XCD-chunked bijective remap (m204), col-tile fastest for A L2 reuse.
// ---------------------------------------------------------------------------
#define TM 128
#define TN 128
#define TKK 32
__launch_bounds__(256)
__global__ void gemm_mfma(const ushort_t* __restrict__ A0, int lda, size_t aStr,
                          const ushort_t* __restrict__ BT0, size_t bStr,
                          const float* __restrict__ bias0, int biasStr,
                          ushort_t* __restrict__ C0, int ldc, size_t cStr,
                          int cShift, int M) {
    __shared__ ushort_t As[2][TM * TKK];   // 2 x 8 KB
    __shared__ ushort_t Bs[2][TN * TKK];   // 2 x 8 KB
    int tid = threadIdx.x;
    int w = tid >> 6, lane = tid & 63;
    int t = blockIdx.z;
    const ushort_t* A  = A0 + (size_t)t * aStr;
    const ushort_t* BT = BT0 + (size_t)t * bStr;
    const float* bias  = bias0 + (size_t)t * biasStr;
    ushort_t* C        = C0 + (size_t)t * cStr;

    // --- XCD-chunked bijective swizzle, col-tile fastest ---
    int nwg  = gridDim.x * gridDim.y;
    int orig = blockIdx.y * gridDim.x + blockIdx.x;
    int q = nwg >> 3, r = nwg & 7;
    int xcd = orig & 7, loc = orig >> 3;
    int wgid = (xcd < r ? xcd * (q + 1) : r * (q + 1) + (xcd - r) * q) + loc;
    int ncol = gridDim.y;
    int rowt = wgid / ncol;
    int colt = wgid - rowt * ncol;
    int bm = rowt * TM;
    int bn = colt * TN;

    int wm = (w & 1) * 64, wn = (w >> 1) * 64;

    floatx4 acc[4][4] = {};

    int srow = lane >> 2;            // 16 rows per cp16 (64 lanes x 16B, 64B rows)
    int scol = (lane & 3) * 8;       // k offset (ushorts)
    int fr = lane & 15, fq = lane >> 4;

#define GEMM_STAGE(b, kc)                                                     \
    {                                                                         \
        _Pragma("unroll")                                                     \
        for (int j = 0; j < 2; j++) {                                         \
            int rr = w * 32 + j * 16;                                         \
            int gr = bm + rr + srow; if (gr >= M) gr = M - 1;                 \
            async_cp16(A + (size_t)gr * lda + (kc) + scol, As[b] + rr * TKK); \
            int gn = bn + rr + srow;                                          \
            async_cp16(BT + (size_t)gn * 256 + (kc) + scol, Bs[b] + rr * TKK);\
        }                                                                     \
    }

    GEMM_STAGE(0, 0);
#pragma unroll
    for (int s = 0; s < 8; s++) {
        int cur = s & 1;
        if (s < 7) {
            GEMM_STAGE(cur ^ 1, (s + 1) * TKK);
            __builtin_amdgcn_s_waitcnt(0x0F74);       // vmcnt(4)
        } else {
            __builtin_amdgcn_s_waitcnt(0x0F70);       // vmcnt(0)
        }
        __syncthreads();

        shortx8 af[4], bf[4];
#pragma unroll
        for (int i = 0; i < 4; i++)
            af[i] = *(const shortx8*)(As[cur] + (wm + i * 16 + fr) * TKK + fq * 8);
#pragma unroll
        for (int j = 0; j < 4; j++)
            bf[j] = *(const shortx8*)(Bs[cur] + (wn + j * 16 + fr) * TKK + fq * 8);
#pragma unroll
        for (int i = 0; i < 4; i++)
#pragma unroll
            for (int j = 0; j < 4; j++)
                acc[i][j] = __builtin_amdgcn_mfma_f32_16x16x32_bf16(af[i], bf[j], acc[i][j], 0, 0, 0);
        __syncthreads();
    }
#undef GEMM_STAGE

#pragma unroll
    for (int i = 0; i < 4; i++) {
#pragma unroll
        for (int j = 0; j < 4; j++) {
            int col = bn + wn + j * 16 + fr;
            float bv = bias[col];
#pragma unroll
            for (int rr = 0; rr < 4; rr++) {
                int row = bm + wm + i * 16 + fq * 4 + rr;
                if (row < M) C[(size_t)row * ldc + cShift + col] = f2b(acc[i][j][rr] + bv);
            }
        }
    }
}

// ---------------------------------------------------------------------------
// CSR build — 8-WAY PRIVATIZED atomics. Theory: ~200us of the total hides in
// count_deg/fill_edges (2 x 1M device-scope atomicAdds onto 400KB => long
// per-cache-line RMW chains, memory-side, cross-XCD). Privatizing the
// counters 8x (cnt8[g][node], g = blockIdx&7 — IDENTICAL grids in count and
// fill so the same edge maps to the same g) spreads the atomics over 8x the
// lines with 8x fewer collisions each. scan emits per-group cursor bases.
// ---------------------------------------------------------------------------
__global__ void count_deg(const int* __restrict__ dst, int* __restrict__ cnt8,
                          int N, int E) {
    int i = blockIdx.x * blockDim.x + threadIdx.x;
    if (i >= 2 * E) return;
    int g = blockIdx.x & 7;
    int et = i / E, e = i - et * E;
    int d = dst[(size_t)et * E + e];
    atomicAdd(&cnt8[g * 2 * N + (1 - et) * N + d], 1);
}

// Stage 1: per-block (256 nodes) scan of deg (= sum over 8 cnt8 planes).
// Writes block-local exclusive into row_ptr[i] (temp) + block total to bsum.
__launch_bounds__(256)
__global__ void scan_blocks(const int* __restrict__ cnt8, int* __restrict__ row_ptr,
                            int* __restrict__ bsum, int n) {
    __shared__ int wsum[4];
    int tid = threadIdx.x, lane = tid & 63, w = tid >> 6;
    int i = blockIdx.x * 256 + tid;
    int v = 0;
    if (i < n) {
#pragma unroll
        for (int g = 0; g < 8; g++) v += cnt8[g * n + i];
    }
    int x = v;
#pragma unroll
    for (int off = 1; off < 64; off <<= 1) {
        int y = __shfl_up(x, off);
        if (lane >= off) x += y;
    }
    if (lane == 63) wsum[w] = x;
    __syncthreads();
    int add = 0;
    if (w > 0) add += wsum[0];
    if (w > 1) add += wsum[1];
    if (w > 2) add += wsum[2];
    int incl = x + add;
    if (i < n) row_ptr[i] = incl - v;         // block-local exclusive (temp)
    if (tid == 255) bsum[blockIdx.x] = incl;  // block total
}

__launch_bounds__(512)
__global__ void scan_tops(int* __restrict__ bsum, int* __restrict__ row_ptr,
                          int nb, int n) {
    __shared__ int wsum[8];
    int tid = threadIdx.x, lane = tid & 63, w = tid >> 6;
    int v = (tid < nb) ? bsum[tid] : 0;
    int x = v;
#pragma unroll
    for (int off = 1; off < 64; off <<= 1) {
        int y = __shfl_up(x, off);
        if (lane >= off) x += y;
    }
    if (lane == 63) wsum[w] = x;
    __syncthreads();
    int add = 0;
    for (int j = 0; j < w; j++) add += wsum[j];
    int incl = x + add;
    if (tid < nb) bsum[tid] = incl - v;    // exclusive block offsets
    if (tid == nb - 1) row_ptr[n] = incl;  // grand total
}

// Stage 3: finalize row_ptr and emit per-group cursor bases:
//   cursor8[g][i] = row_ptr[i] + sum_{g'<g} cnt8[g'][i]
__launch_bounds__(256)
__global__ void scan_apply(const int* __restrict__ cnt8, const int* __restrict__ bsum,
                           int* __restrict__ row_ptr, int* __restrict__ cursor8, int n) {
    int i = blockIdx.x * 256 + threadIdx.x;
    if (i >= n) return;
    int e = row_ptr[i] + bsum[blockIdx.x];
    row_ptr[i] = e;
    int run = e;
#pragma unroll
    for (int g = 0; g < 8; g++) {
        cursor8[g * n + i] = run;
        run += cnt8[g * n + i];
    }
}

__global__ void fill_edges(const int* __restrict__ src, const int* __restrict__ dst,
                           int* __restrict__ cursor8, int* __restrict__ ebuf,
                           int N, int E) {
    int i = blockIdx.x * blockDim.x + threadIdx.x;
    if (i >= 2 * E) return;
    int g = blockIdx.x & 7;
    int et = i / E, e = i - et * E;
    int d = dst[(size_t)et * E + e];
    int s = src[(size_t)et * E + e];
    int pos = atomicAdd(&cursor8[g * 2 * N + (1 - et) * N + d], 1);
    ebuf[pos] = s;
}

// ---------------------------------------------------------------------------
// Node-centric aggregation, split per dst-type into two dispatches (wbase)
// to keep the second-tier kernels visible in the top-5 profile.
// One wave per destination node, two 32-lane halves on even/odd CSR edges,
// depth-2 register pipeline, packed-f32 math. ~Structural floor (~3.8 TB/s
// random 1KB fetches from a 150MB set).
// ---------------------------------------------------------------------------
__launch_bounds__(256)
__global__ void node_aggregate(ushort_t* __restrict__ QKV, const float* __restrict__ mu,
                               const int* __restrict__ row_ptr, const int* __restrict__ ebuf,
                               int N, int wbase) {
    int wid = ((blockIdx.x * blockDim.x + threadIdx.x) >> 6) + wbase;
    int lane = threadIdx.x & 63;
    if (wid >= wbase + N) return;
    int dt = (wid >= N) ? 1 : 0;
    int et = 1 - dt;
    int l = lane & 31;
    int half = lane >> 5;
    int h = l >> 2;

    uint4 qu = ((const uint4*)(QKV + (size_t)wid * 768))[l];
    floatx2 q01 = b2x2(qu.x), q23 = b2x2(qu.y), q45 = b2x2(qu.z), q67 = b2x2(qu.w);
    float sc = mu[et * H + h] * 0.17677669529663687f;  // 1/sqrt(32)
    int beg = row_ptr[wid], end = row_ptr[wid + 1];
    const ushort_t* KVb = QKV + (size_t)et * N * 768 + l * 8;

    floatx2 a01 = {0.f, 0.f}, a23 = {0.f, 0.f}, a45 = {0.f, 0.f}, a67 = {0.f, 0.f};
    float ssum = 0.f;

#define AGG_COMPUTE(kk, vv)                                              \
    {                                                                    \
        floatx2 pv = q01 * b2x2(kk.x);                                   \
        pv += q23 * b2x2(kk.y);                                          \
        pv += q45 * b2x2(kk.z);                                          \
        pv += q67 * b2x2(kk.w);                                          \
        float pp = pv.x + pv.y;                                          \
        pp += __shfl_xor(pp, 1);                                         \
        pp += __shfl_xor(pp, 2);                                         \
        float ex = __expf(pp * sc);                                      \
        ssum += ex;                                                      \
        floatx2 e2 = {ex, ex};                                           \
        a01 += e2 * b2x2(vv.x);                                          \
        a23 += e2 * b2x2(vv.y);                                          \
        a45 += e2 * b2x2(vv.z);                                          \
        a67 += e2 * b2x2(vv.w);                                          \
    }

    int p = beg + half;
    uint4 kA = {}, vA = {}, kB = {}, vB = {};
    int sC = 0, sD = 0;
    if (p < end) {
        int sA = ebuf[p];
        const ushort_t* r0 = KVb + (size_t)sA * 768;
        kA = *(const uint4*)(r0 + 256);
        vA = *(const uint4*)(r0 + 512);
        sC = (p + 4 < end) ? ebuf[p + 4] : sA;
    }
    if (p + 2 < end) {
        int sB = ebuf[p + 2];
        const ushort_t* r1 = KVb + (size_t)sB * 768;
        kB = *(const uint4*)(r1 + 256);
        vB = *(const uint4*)(r1 + 512);
        sD = (p + 6 < end) ? ebuf[p + 6] : sB;
    }
    while (p < end) {
        uint4 nk = kA, nv = vA;
        int sE = sC;
        if (p + 4 < end) {
            const ushort_t* rr = KVb + (size_t)sC * 768;
            nk = *(const uint4*)(rr + 256);
            nv = *(const uint4*)(rr + 512);
            if (p + 8 < end) sE = ebuf[p + 8];
        }
        AGG_COMPUTE(kA, vA);
        kA = nk; vA = nv; sC = sE;
        p += 2;
        if (p >= end) break;
        nk = kB; nv = vB; sE = sD;
        if (p + 4 < end) {
            const ushort_t* rr = KVb + (size_t)sD * 768;
            nk = *(const uint4*)(rr + 256);
            nv = *(const uint4*)(rr + 512);
            if (p + 8 < end) sE = ebuf[p + 8];
        }
        AGG_COMPUTE(kB, vB);
        kB = nk; vB = nv; sD = sE;
        p += 2;
    }
#undef AGG_COMPUTE

    ssum += __shfl_xor(ssum, 32);
    a01.x += __shfl_xor(a01.x, 32); a01.y += __shfl_xor(a01.y, 32);
    a23.x += __shfl_xor(a23.x, 32); a23.y += __shfl_xor(a23.y, 32);
    a45.x += __shfl_xor(a45.x, 32); a45.y += __shfl_xor(a45.y, 32);
    a67.x += __shfl_xor(a67.x, 32); a67.y += __shfl_xor(a67.y, 32);
    float r = (ssum > 0.f) ? 1.0f / ssum : 0.0f;
    if (half == 0) {
        ushortx8 hv;
        hv[0] = f2b(a01.x * r); hv[1] = f2b(a01.y * r);
        hv[2] = f2b(a23.x * r); hv[3] = f2b(a23.y * r);
        hv[4] = f2b(a45.x * r); hv[5] = f2b(a45.y * r);
        hv[6] = f2b(a67.x * r); hv[7] = f2b(a67.y * r);
        ((ushortx8*)(QKV + (size_t)wid * 768))[l] = hv;
    }
}

// ---------------------------------------------------------------------------
// out = LN(alpha*trans + (1-alpha)*feats_bf16) * ln_w + ln_b.
// Wave per row. trans lives in the K-section of QKV (stride 768);
// feats read as bf16 from featsb.
// ---------------------------------------------------------------------------
__launch_bounds__(256)
__global__ void skip_ln(const ushort_t* __restrict__ trans, const ushort_t* __restrict__ featsb,
                        const float* __restrict__ lnw, const float* __restrict__ lnb,
                        const float* __restrict__ skip, float* __restrict__ out, int N) {
    int wid = (blockIdx.x * blockDim.x + threadIdx.x) >> 6;
    int lane = threadIdx.x & 63;
    if (wid >= 2 * N) return;
    int t = (wid >= N) ? 1 : 0;
    float alpha = 1.0f / (1.0f + __expf(-skip[t]));
    float beta = 1.0f - alpha;
    ushort4 tu = ((const ushort4*)(trans + (size_t)wid * 768))[lane];
    ushort4 fu = ((const ushort4*)(featsb + (size_t)wid * D))[lane];
    float x0 = alpha * b2f(tu.x) + beta * b2f(fu.x);
    float x1 = alpha * b2f(tu.y) + beta * b2f(fu.y);
    float x2 = alpha * b2f(tu.z) + beta * b2f(fu.z);
    float x3 = alpha * b2f(tu.w) + beta * b2f(fu.w);
    float s  = x0 + x1 + x2 + x3;
    float sq = x0 * x0 + x1 * x1 + x2 * x2 + x3 * x3;
#pragma unroll
    for (int off = 1; off < 64; off <<= 1) {
        s  += __shfl_xor(s,  off);
        sq += __shfl_xor(sq, off);
    }
    float mean = s * (1.0f / 256.0f);
    float var  = sq * (1.0f / 256.0f) - mean * mean;
    float r = rsqrtf(var + 1e-5f);
    float4 w4 = ((const float4*)(lnw + t * D))[lane];
    float4 b4 = ((const float4*)(lnb + t * D))[lane];
    float4 o;
    o.x = (x0 - mean) * r * w4.x + b4.x;
    o.y = (x1 - mean) * r * w4.y + b4.y;
    o.z = (x2 - mean) * r * w4.z + b4.z;
    o.w = (x3 - mean) * r * w4.w + b4.w;
    ((float4*)(out + (size_t)wid * D))[lane] = o;
}

extern "C" void kernel_launch(void* const* d_in, const int* in_sizes, int n_in,
                              void* d_out, int out_size, void* d_ws, size_t ws_size,
                              hipStream_t stream) {
    const float* feats = (const float*)d_in[0];
    const float* Wk    = (const float*)d_in[1];
    const float* bk    = (const float*)d_in[2];
    const float* Wq    = (const float*)d_in[3];
    const float* bq    = (const float*)d_in[4];
    const float* Wv    = (const float*)d_in[5];
    const float* bv    = (const float*)d_in[6];
    const float* Wa    = (const float*)d_in[7];
    const float* ba    = (const float*)d_in[8];
    const float* ln_w  = (const float*)d_in[9];
    const float* ln_b  = (const float*)d_in[10];
    const float* skip  = (const float*)d_in[11];
    const float* mu    = (const float*)d_in[12];
    const float* w_att = (const float*)d_in[13];
    const float* w_msg = (const float*)d_in[14];
    const int*   src   = (const int*)d_in[15];
    const int*   dst   = (const int*)d_in[16];
    float* out = (float*)d_out;

    const int N = in_sizes[0] / (2 * D);
    const int E = in_sizes[15] / 2;
    const int NN = 2 * N;
    const size_t ND2 = 2 * (size_t)N * D;     // 25.6M elems

    // Workspace layout (float units). ~220 MB total.
    float* ws = (float*)d_ws;
    size_t off = 0;
    float* Wkc  = ws + off; off += 2 * (size_t)D * D;
    float* Wvc  = ws + off; off += 2 * (size_t)D * D;
    float* bkc  = ws + off; off += 2 * D;
    float* bvc  = ws + off; off += 2 * D;
    float* bias_all = ws + off; off += 2 * 768;
    ushort_t* WT_all = (ushort_t*)(ws + off); off += 2 * 768 * 256 / 2;
    ushort_t* WaT    = (ushort_t*)(ws + off); off += 2 * 256 * 256 / 2;
    ushort_t* featsb = (ushort_t*)(ws + off); off += ND2 / 2;   // bf16 feats (stays intact)
    ushort_t* QKV    = (ushort_t*)(ws + off); off += 2 * (size_t)N * 768 / 2;
    int* cnt8    = (int*)(ws + off); off += 8 * (size_t)NN;
    int* cursor8 = (int*)(ws + off); off += 8 * (size_t)NN;
    int* row_ptr = (int*)(ws + off); off += NN + 1;
    int* ebuf    = (int*)(ws + off); off += 2 * (size_t)E;
    int* bsum    = (int*)(ws + off); off += 512;

    const int nb = (NN + 255) / 256;          // scan blocks (<=512 required)

    // --- CSR build (8-way privatized atomics) ---
    zero_int<<<(8 * NN + 255) / 256, 256, 0, stream>>>(cnt8, 8 * NN);
    count_deg<<<(2 * E + 255) / 256, 256, 0, stream>>>(dst, cnt8, N, E);
    scan_blocks<<<nb, 256, 0, stream>>>(cnt8, row_ptr, bsum, NN);
    scan_tops<<<1, 512, 0, stream>>>(bsum, row_ptr, nb, NN);
    scan_apply<<<nb, 256, 0, stream>>>(cnt8, bsum, row_ptr, cursor8, NN);
    fill_edges<<<(2 * E + 255) / 256, 256, 0, stream>>>(src, dst, cursor8, ebuf, N, E);

    // --- weight prep ---
    fold_weights<<<dim3(D, 2, 2), 256, 0, stream>>>(Wk, bk, Wv, bv, w_att, w_msg,
                                                    Wkc, bkc, Wvc, bvc);
    pack_weights<<<(2 * 768 * 256 + 2 * 256 * 256 + 255) / 256, 256, 0, stream>>>(
        Wq, bq, Wkc, bkc, Wvc, bvc, Wa, WT_all, WaT, bias_all);

    // --- feats -> bf16 ---
    cvt_bf16<<<(unsigned)((ND2 / 4 + 255) / 256), 256, 0, stream>>>(feats, featsb, ND2 / 4);

    // --- fused Q|K|V GEMM, both ntypes (grid.z): (N x 256) @ (256 x 768) ---
    dim3 qkv_grid((N + TM - 1) / TM, 768 / TN, 2);
    gemm_mfma<<<qkv_grid, 256, 0, stream>>>(featsb, D, (size_t)N * D,
                                            WT_all, (size_t)768 * 256,
                                            bias_all, 768,
                                            QKV, 768, (size_t)N * 768, 0, N);

    // --- attention aggregation, split per dst-type ---
    node_aggregate<<<((size_t)N * 64 + 255) / 256, 256, 0, stream>>>(QKV, mu, row_ptr, ebuf, N, 0);
    node_aggregate<<<((size_t)N * 64 + 255) / 256, 256, 0, stream>>>(QKV, mu, row_ptr, ebuf, N, N);

    // --- trans = H @ Wa + ba -> K-section of QKV (cols 256..511, bf16) ---
    dim3 tr_grid((N + TM - 1) / TM, 256 / TN, 2);
    gemm_mfma<<<tr_grid, 256, 0, stream>>>(QKV, 768, (size_t)N * 768,
                                           WaT, (size_t)256 * 256,
                                           ba, 256,
                                           QKV, 768, (size_t)N * 768, 256, N);

    skip_ln<<<(NN * 64 + 255) / 256, 256, 0, stream>>>(QKV + 256, featsb,
                                                       ln_w, ln_b, skip, out, N);
}